// Round 6
// baseline (176.815 us; speedup 1.0000x reference)
//
#include <hip/hip_runtime.h>

// RoiCut: out[i, c, y, x] = fm[assoc[i], c, y0_i + y, x0_i + x]
// fm: [8, 256, 200, 200] fp32, boxes_yx: [512, 2] int32 (y0, x0), assoc: [512] int32
// out: [512, 256, 32, 32] fp32
//
// R5 strategy: R4 + in-block software pipeline (T14 issue-early/write-late).
//  - block = (sample, channel): stage half-plane H0 (80,000 B LDS), then ISSUE
//    H1's global loads BEFORE the H0 box/store phase -> HBM load latency and
//    read stream overlap the store phase instead of serializing at barriers.
//    (R4 showed co-resident blocks are phase-locked; overlap must be in-block.)
//  - reads stay exact-once & perfectly coalesced; no inter-block reuse exists.
//  - grouping kernel = 8-bin counting scatter (was 45-phase bitonic): box order
//    within a sample is irrelevant (disjoint output tiles), so LDS-atomic order
//    nondeterminism does not affect the output bytes.
//  - non-temporal dwordx4 stores, full 64B lines.

typedef float v4f __attribute__((ext_vector_type(4)));

constexpr int C_     = 256;
constexpr int H_     = 200;
constexpr int W_     = 200;
constexpr int BOX_   = 32;
constexpr int N_     = 512;
constexpr int B_     = 8;
constexpr int PLANE  = H_ * W_;       // 40000 floats
constexpr int HROWS  = 100;           // rows per half
constexpr int HLDS   = HROWS * W_;    // 20000 floats = 80,000 B
constexpr int HLDS4  = HLDS / 4;      // 5000 float4

__global__ __launch_bounds__(512) void group_boxes_kernel(
    const int* __restrict__ boxes,
    const int* __restrict__ assoc,
    unsigned int* __restrict__ keys,
    int* __restrict__ starts)
{
    __shared__ int cnt[B_];
    __shared__ int base[B_ + 1];
    int t = threadIdx.x;   // 512 threads, one per box

    if (t < B_) cnt[t] = 0;
    __syncthreads();

    int y0 = boxes[2 * t];
    int x0 = boxes[2 * t + 1];
    y0 = min(max(y0, 0), H_ - BOX_);
    x0 = min(max(x0, 0), W_ - BOX_);
    int a = assoc[t];
    int pos = atomicAdd(&cnt[a], 1);   // LDS atomic; order nondeterminism is benign
    __syncthreads();

    if (t == 0) {
        int s = 0;
        for (int i = 0; i < B_; ++i) { base[i] = s; s += cnt[i]; }
        base[B_] = s;
    }
    __syncthreads();

    // key: [y0:8 | x0:8 | idx:9]
    keys[base[a] + pos] = ((unsigned int)y0 << 17) | ((unsigned int)x0 << 9) | (unsigned int)t;
    if (t <= B_) starts[t] = base[t];
}

__global__ __launch_bounds__(1024, 8) void roicut_kernel(
    const float* __restrict__ fm,
    const unsigned int* __restrict__ keys,
    const int* __restrict__ starts,
    float* __restrict__ out)
{
    extern __shared__ float lds[];   // 80,000 B = half plane (100 rows x 200)

    int bid = blockIdx.x;
    int c = bid & 255;               // channel
    int a = bid >> 8;                // sample
    int t = threadIdx.x;             // 1024 threads

    int b0 = starts[a], b1 = starts[a + 1];
    int sub = t >> 8;                // 0..3 (4 waves each)
    int q   = t & 255;               // pixel-quad within box tile
    int y   = q >> 3;                // 0..31
    int xg  = (q & 7) << 2;          // 0,4,...,28

    const v4f* src = (const v4f*)(fm + (size_t)(a * C_ + c) * PLANE);
    v4f* l4 = (v4f*)lds;
    bool tail = t < (HLDS4 - 4096);  // t < 904

    // ---- stage H0 (rows 0..99) ----
    v4f r0 = src[t];
    v4f r1 = src[t + 1024];
    v4f r2 = src[t + 2048];
    v4f r3 = src[t + 3072];
    v4f r4;
    if (tail) r4 = src[t + 4096];
    l4[t]        = r0;
    l4[t + 1024] = r1;
    l4[t + 2048] = r2;
    l4[t + 3072] = r3;
    if (tail) l4[t + 4096] = r4;
    __syncthreads();

    // ---- ISSUE H1 loads now (latency hides under H0's store phase) ----
    const v4f* src1 = src + HLDS4;
    r0 = src1[t];
    r1 = src1[t + 1024];
    r2 = src1[t + 2048];
    r3 = src1[t + 3072];
    if (tail) r4 = src1[t + 4096];
    __builtin_amdgcn_sched_barrier(0);   // keep the loads issued above the store loop

    // ---- process H0 ----
    {
        const int hbase = 0;
        for (int b = b0; b < b1; b += 4) {
            int bb = b + sub;
            if (bb < b1) {
                unsigned int v = keys[bb];
                int y0 = (v >> 17) & 255;
                int x0 = (v >> 9) & 255;
                int i  = (int)(v & 511u);
                int ly = y0 + y - hbase;
                if (ly >= 0 && ly < HROWS) {
                    const float* p = lds + ly * W_ + (x0 + xg);
                    v4f vv;
                    vv[0] = p[0]; vv[1] = p[1]; vv[2] = p[2]; vv[3] = p[3];
                    v4f* dst = (v4f*)(out + (((size_t)i << 18) + ((size_t)c << 10) + (size_t)(q << 2)));
                    __builtin_nontemporal_store(vv, dst);
                }
            }
        }
    }
    __syncthreads();   // H0 LDS reads done; drains H1 loads (needed next anyway)

    // ---- write + process H1 (rows 100..199) ----
    l4[t]        = r0;
    l4[t + 1024] = r1;
    l4[t + 2048] = r2;
    l4[t + 3072] = r3;
    if (tail) l4[t + 4096] = r4;
    __syncthreads();

    {
        const int hbase = HROWS;
        for (int b = b0; b < b1; b += 4) {
            int bb = b + sub;
            if (bb < b1) {
                unsigned int v = keys[bb];
                int y0 = (v >> 17) & 255;
                int x0 = (v >> 9) & 255;
                int i  = (int)(v & 511u);
                int ly = y0 + y - hbase;
                if (ly >= 0 && ly < HROWS) {
                    const float* p = lds + ly * W_ + (x0 + xg);
                    v4f vv;
                    vv[0] = p[0]; vv[1] = p[1]; vv[2] = p[2]; vv[3] = p[3];
                    v4f* dst = (v4f*)(out + (((size_t)i << 18) + ((size_t)c << 10) + (size_t)(q << 2)));
                    __builtin_nontemporal_store(vv, dst);
                }
            }
        }
    }
}

extern "C" void kernel_launch(void* const* d_in, const int* in_sizes, int n_in,
                              void* d_out, int out_size, void* d_ws, size_t ws_size,
                              hipStream_t stream) {
    const float* fm    = (const float*)d_in[0];
    const int*   boxes = (const int*)d_in[1];
    const int*   assoc = (const int*)d_in[2];
    float*       out   = (float*)d_out;

    unsigned int* keys   = (unsigned int*)d_ws;        // 512 u32
    int*          starts = (int*)d_ws + N_;            // 9 ints

    // allow 80,000 B dynamic LDS (host-side attribute; idempotent, no stream op)
    (void)hipFuncSetAttribute((const void*)roicut_kernel,
                              hipFuncAttributeMaxDynamicSharedMemorySize,
                              HLDS * (int)sizeof(float));

    group_boxes_kernel<<<1, N_, 0, stream>>>(boxes, assoc, keys, starts);

    int grid = B_ * C_;   // 2048 blocks: one per (sample, channel), both halves pipelined
    roicut_kernel<<<grid, 1024, HLDS * sizeof(float), stream>>>(fm, keys, starts, out);
}